// Round 6
// baseline (365.423 us; speedup 1.0000x reference)
//
#include <hip/hip_runtime.h>

typedef short bf16x8 __attribute__((ext_vector_type(8)));
typedef float f32x4 __attribute__((ext_vector_type(4)));
typedef float f32x16 __attribute__((ext_vector_type(16)));
typedef unsigned int u32;
typedef u32 u32x4 __attribute__((ext_vector_type(4)));
typedef unsigned short u16;

#define B_    32
#define N_    1025
#define H_    8
#define DIM_  512
#define M_    (B_*N_)      // 32800
#define QP_   1152         // qn row pitch per bh
#define BIP_  1152         // bias_r i pitch
#define NT_   34           // KV/bias tiles incl. 1 pad tile (prefetch guard-free)
#define KVSZ_ (NT_*2048)   // per-bh u16 size of kn2/v2
#define BT_   (BIP_*32)    // bias tile stride (elements)
#define SCALE_ 0.125f
#define LOG2E_ 1.4426950408889634f

__device__ __forceinline__ u16 f2bf(float f){
  unsigned u = __builtin_bit_cast(unsigned, f);
  u += 0x7FFFu + ((u >> 16) & 1u);
  return (u16)(u >> 16);
}
__device__ __forceinline__ u32 cvtpk(float a, float b){
  u32 r;
  asm("v_cvt_pk_bf16_f32 %0, %1, %2" : "=v"(r) : "v"(a), "v"(b));
  return r;
}
__device__ __forceinline__ void pswap(u32 &a, u32 &b){
  asm("v_permlane32_swap_b32 %0, %1" : "+v"(a), "+v"(b));
}
__device__ __forceinline__ void gll16(const u16* g, u16* l){
  __builtin_amdgcn_global_load_lds((const __attribute__((address_space(1))) u16*)(g),
                                   (__attribute__((address_space(3))) u16*)(l), 16, 0, 0);
}

// ---------------- prep kernels ----------------
__global__ __launch_bounds__(256)
void k_conv_x(const float* __restrict__ x, u16* __restrict__ o, int n4){
  int i = blockIdx.x*256 + threadIdx.x;
  if (i >= n4) return;
  float4 v = ((const float4*)x)[i];
  ushort4 r;
  r.x = f2bf(v.x); r.y = f2bf(v.y); r.z = f2bf(v.z); r.w = f2bf(v.w);
  ((ushort4*)o)[i] = r;
}

__global__ __launch_bounds__(256)
void k_transpose(const float* __restrict__ w, u16* __restrict__ wt, int R, int C){
  int i = blockIdx.x*256 + threadIdx.x;
  if (i >= R*C) return;
  int n = i / R, k = i - n*R;
  wt[i] = f2bf(w[k*C + n]);
}

// bias_f[h][tj(34)][i(1152)][hi(2)][16 regs] in f32; value = pe*log2e (masked)
__global__ __launch_bounds__(256)
void k_biasr(const int* __restrict__ idx, const float* __restrict__ pe, float* __restrict__ br){
  int i_lin = blockIdx.x*256 + threadIdx.x;  // 8*34*1152*32 total
  int v = i_lin & 15, hi = (i_lin>>4)&1;
  int t1 = i_lin >> 5;
  int i = t1 % 1152;
  int t2 = t1 / 1152;
  int tj = t2 % NT_;
  int h = t2 / NT_;
  int j = tj*32 + (v&3) + 8*(v>>2) + 4*hi;
  float val;
  if (j >= 1 && j <= 1024 && i >= 1 && i <= 1024)
    val = pe[idx[(i-1)*1024 + (j-1)]*8 + h] * LOG2E_;
  else
    val = (j <= 1024) ? 0.f : -1e9f;
  br[i_lin] = val;
}

// zero tails: qn rows [1025,1152); kn2 tile-32 j in [1025,1056); v2 same
__global__ __launch_bounds__(256)
void k_ztail(u16* __restrict__ qn, u16* __restrict__ kn2, u16* __restrict__ v2){
  int i = blockIdx.x*256 + threadIdx.x;
  if (i < 2080768){
    int bh = i / (127*64); int r = i - bh*(127*64);
    qn[((size_t)bh*QP_ + 1025 + (r>>6))*64 + (r&63)] = 0;
  } else if (i < 2588672){
    int k = i - 2080768; int bh = k/1984; int r = k - bh*1984;
    int n = 1025 + (r>>6), d = r & 63;
    kn2[(size_t)bh*KVSZ_ + 65536 + ((d>>3)<<8) + ((n&31)<<3) + (d&7)] = 0;
  } else if (i < 3096576){
    int k = i - 2588672; int bh = k/1984; int r = k - bh*1984;
    int n = 1025 + (r>>6), d = r & 63;
    v2[(size_t)bh*KVSZ_ + 65536 + (((n>>3)&3)<<9) + (d<<3) + (n&7)] = 0;
  }
}

// ---------------- QKV GEMM (128x128 tile) + fused RMSNorm / rearrange ----------------
// grid 3084 = 257 M-tiles x 12 N-tiles; 4 waves 2x2, each 64x64 quadrant
__global__ __launch_bounds__(256)
void k_qkv(const u16* __restrict__ xb, const u16* __restrict__ wT, const float* __restrict__ g,
           u16* __restrict__ qn, u16* __restrict__ kn2, u16* __restrict__ v2){
  __shared__ u16 sh[16384];   // As[2][4096] | Bs[2][4096]
  const int tid = threadIdx.x;
  const int lane = tid & 63, wid = tid >> 6;
  const int lg = lane >> 4, lr = lane & 15;
  const int wm = wid >> 1, wn = wid & 1;

  // bijective XCD swizzle (nwg=3084, q=385, r=4); within XCD: nt fastest
  int orig = blockIdx.x;
  int xcd = orig & 7, idx = orig >> 3;
  int wgid = (xcd < 4 ? xcd*386 : 1544 + (xcd-4)*385) + idx;
  int mt = wgid / 12, nt = wgid - mt*12;
  const int m0 = mt*128, n0 = nt*128;
  const int qkv_t = nt >> 2;
  const int h = ((nt & 3) << 1) + wn;

  const int srow = tid >> 2;
  const int schunk = (tid & 3) ^ ((tid >> 3) & 3);
  const u16* asrc = xb + (size_t)(m0 + srow)*DIM_ + schunk*8;
  const u16* bsrc = wT + (size_t)(n0 + srow)*DIM_ + schunk*8;
  const int rsw = (lg ^ ((lr>>1)&3)) << 3;

  u16* As = sh;
  u16* Bs = sh + 8192;

  f32x4 acc[4][4];
#pragma unroll
  for (int m=0;m<4;++m)
#pragma unroll
    for (int n=0;n<4;++n) acc[m][n] = {0.f,0.f,0.f,0.f};

  gll16(asrc,            As + wid*512);
  gll16(asrc + 64*DIM_,  As + 2048 + wid*512);
  gll16(bsrc,            Bs + wid*512);
  gll16(bsrc + 64*DIM_,  Bs + 2048 + wid*512);

  for (int s=0; s<16; ++s){
    const int cur = s & 1;
    __syncthreads();
    if (s < 15){
      const int ko = (s+1)*32;
      gll16(asrc + ko,           As + (cur^1)*4096 + wid*512);
      gll16(asrc + ko + 64*DIM_, As + (cur^1)*4096 + 2048 + wid*512);
      gll16(bsrc + ko,           Bs + (cur^1)*4096 + wid*512);
      gll16(bsrc + ko + 64*DIM_, Bs + (cur^1)*4096 + 2048 + wid*512);
    }
    bf16x8 af[4], bf[4];
#pragma unroll
    for (int m=0;m<4;++m) af[m] = *(const bf16x8*)(As + cur*4096 + (64*wm+16*m+lr)*32 + rsw);
#pragma unroll
    for (int n=0;n<4;++n) bf[n] = *(const bf16x8*)(Bs + cur*4096 + (64*wn+16*n+lr)*32 + rsw);
    __builtin_amdgcn_s_setprio(1);
#pragma unroll
    for (int m=0;m<4;++m)
#pragma unroll
      for (int n=0;n<4;++n)
        acc[m][n] = __builtin_amdgcn_mfma_f32_16x16x32_bf16(af[m], bf[n], acc[m][n], 0, 0, 0);
    __builtin_amdgcn_s_setprio(0);
  }

  // unified epilogue: rows 64*wm+16m+4lg+r, head h, d = 16n+lr
  float gv[4];
#pragma unroll
  for (int n=0;n<4;++n)
    gv[n] = (qkv_t==0) ? g[16*n+lr]*(SCALE_*LOG2E_) : (qkv_t==1 ? g[16*n+lr] : 1.f);

#pragma unroll
  for (int m=0;m<4;++m){
    float rstd[4];
    if (qkv_t < 2){
#pragma unroll
      for (int r=0;r<4;++r){
        float s = 0.f;
#pragma unroll
        for (int n=0;n<4;++n) s += acc[m][n][r]*acc[m][n][r];
        s += __shfl_xor(s, 1); s += __shfl_xor(s, 2);
        s += __shfl_xor(s, 4); s += __shfl_xor(s, 8);
        rstd[r] = rsqrtf(s*(1.f/64.f) + 1e-6f);
      }
    } else {
#pragma unroll
      for (int r=0;r<4;++r) rstd[r] = 1.f;
    }
#pragma unroll
    for (int r=0;r<4;++r){
      int mg = m0 + 64*wm + 16*m + 4*lg + r;
      if (mg < M_){
        int b = mg / N_, pos = mg - b*N_;
        int bh = b*H_ + h;
#pragma unroll
        for (int n=0;n<4;++n){
          int d = 16*n + lr;
          u16 val = f2bf(acc[m][n][r]*rstd[r]*gv[n]);
          if (qkv_t == 0)
            qn[((size_t)bh*QP_ + pos)*64 + d] = val;
          else if (qkv_t == 1)
            kn2[(size_t)bh*KVSZ_ + (pos>>5)*2048 + ((d>>3)<<8) + ((pos&31)<<3) + (d&7)] = val;
          else
            v2[(size_t)bh*KVSZ_ + (pos>>5)*2048 + (((pos>>3)&3)<<9) + (d<<3) + (pos&7)] = val;
        }
      }
    }
  }
}

// ---------------- flash attention: fixed-max, f32-bias-as-C, 2-tile pairs ----------------
// grid 2304 = 8 XCD-chunks x (32 b x 9 qt); 4 waves x 32 q-rows = 128-row q-block
#define TILE(buf, off, CB) do { \
  f32x16 s = (CB); \
  __builtin_amdgcn_s_setprio(1); \
  _Pragma("unroll") \
  for (int c=0;c<4;++c){ \
    bf16x8 kf = *(const bf16x8*)(&Ks[buf][0] + (off) + (2*c + hi)*256 + il*8); \
    s = __builtin_amdgcn_mfma_f32_32x32x16_bf16(kf, qf[c], s, 0, 0, 0); \
  } \
  __builtin_amdgcn_s_setprio(0); \
  _Pragma("unroll") \
  for (int r=0;r<16;++r) s[r] = __builtin_amdgcn_exp2f(s[r]); \
  u32 X0 = cvtpk(s[0],s[1]),   X1 = cvtpk(s[2],s[3]); \
  u32 Y0 = cvtpk(s[4],s[5]),   Y1 = cvtpk(s[6],s[7]); \
  u32 X2 = cvtpk(s[8],s[9]),   X3 = cvtpk(s[10],s[11]); \
  u32 Y2 = cvtpk(s[12],s[13]), Y3 = cvtpk(s[14],s[15]); \
  pswap(X0, Y0); pswap(X1, Y1); pswap(X2, Y2); pswap(X3, Y3); \
  u32x4 w0 = {X0, X1, Y0, Y1}; \
  u32x4 w1 = {X2, X3, Y2, Y3}; \
  bf16x8 pv0 = __builtin_bit_cast(bf16x8, w0); \
  bf16x8 pv1 = __builtin_bit_cast(bf16x8, w1); \
  __builtin_amdgcn_s_setprio(1); \
  _Pragma("unroll") \
  for (int c2=0;c2<2;++c2){ \
    bf16x8 pv = c2 ? pv1 : pv0; \
    const u16* vb = &Vs[buf][0] + (off) + (2*c2 + hi)*512; \
    bf16x8 vfA = *(const bf16x8*)(vb + il*8); \
    bf16x8 vfB = *(const bf16x8*)(vb + 256 + il*8); \
    oA = __builtin_amdgcn_mfma_f32_32x32x16_bf16(vfA, pv, oA, 0, 0, 0); \
    oB = __builtin_amdgcn_mfma_f32_32x32x16_bf16(vfB, pv, oB, 0, 0, 0); \
    oS = __builtin_amdgcn_mfma_f32_32x32x16_bf16(onesf, pv, oS, 0, 0, 0); \
  } \
  __builtin_amdgcn_s_setprio(0); \
} while(0)

__global__ __launch_bounds__(256, 3)
void k_attn2(const u16* __restrict__ qn, const u16* __restrict__ kn2, const u16* __restrict__ v2,
             const float* __restrict__ br, u16* __restrict__ ao){
  __shared__ u16 Ks[2][4096];
  __shared__ u16 Vs[2][4096];
  const int tid = threadIdx.x;
  const int lane = tid & 63, wave = tid >> 6;
  const int il = lane & 31, hi = lane >> 5;
  int wg = ((blockIdx.x & 7) * 288) + (blockIdx.x >> 3);
  int h = wg / 288;
  int rem = wg - h*288;
  int b = rem / 9, qt = rem - (rem/9)*9;
  int bh = b*8 + h;
  int i0 = qt*128 + wave*32;

  // Q fragments (hoisted; q pre-scaled by SCALE*log2e in k_qkv)
  const u16* qp = qn + ((size_t)bh*QP_ + (i0 + il))*64 + hi*8;
  bf16x8 qf[4];
#pragma unroll
  for (int c=0;c<4;++c) qf[c] = *(const bf16x8*)(qp + 16*c);

  const u16* ksrc = kn2 + (size_t)bh*KVSZ_ + tid*8;
  const u16* vsrc = v2  + (size_t)bh*KVSZ_ + tid*8;

  // stage pair 0 (tiles 0,1) into buf 0
  gll16(ksrc,        &Ks[0][wave*512]);
  gll16(ksrc + 2048, &Ks[0][2048 + wave*512]);
  gll16(vsrc,        &Vs[0][wave*512]);
  gll16(vsrc + 2048, &Vs[0][2048 + wave*512]);

  f32x16 oA, oB, oS;
#pragma unroll
  for (int r=0;r<16;++r){ oA[r]=0.f; oB[r]=0.f; oS[r]=0.f; }

  const bf16x8 onesf = {0x3F80,0x3F80,0x3F80,0x3F80,0x3F80,0x3F80,0x3F80,0x3F80};

  const float* bptr = br + ((size_t)(h*NT_)*BIP_ + (i0 + il))*32 + hi*16;
  f32x16 cbE = *(const f32x16*)(bptr);
  f32x16 cbO = *(const f32x16*)(bptr + BT_);

  for (int t=0; t<16; ++t){
    const int cur = t & 1;
    __syncthreads();
    {
      const int base = (2*t+2)*2048;   // t=15 -> tiles 32,33 (pad tile valid)
      gll16(ksrc + base,        &Ks[cur^1][wave*512]);
      gll16(ksrc + base + 2048, &Ks[cur^1][2048 + wave*512]);
      gll16(vsrc + base,        &Vs[cur^1][wave*512]);
      gll16(vsrc + base + 2048, &Vs[cur^1][2048 + wave*512]);
    }
    TILE(cur, 0, cbE);
    cbE = *(const f32x16*)(bptr + 2*BT_);
    TILE(cur, 2048, cbO);
    cbO = *(const f32x16*)(bptr + 3*BT_);
    bptr += 2*BT_;
  }
  // tail: tile 32 in buf 0
  __syncthreads();
  TILE(0, 0, cbE);

  int i = i0 + il;
  if (i < N_){
    float inv = 1.f / oS[0];
    u16* op = ao + ((size_t)(b*N_ + i))*DIM_ + h*64;
#pragma unroll
    for (int q=0;q<4;++q)
#pragma unroll
      for (int pr=0;pr<2;++pr){
        int d0 = 8*q + 4*hi + 2*pr;
        u32 wA = cvtpk(oA[4*q+2*pr]*inv, oA[4*q+2*pr+1]*inv);
        u32 wB = cvtpk(oB[4*q+2*pr]*inv, oB[4*q+2*pr+1]*inv);
        *(u32*)(op + d0) = wA;
        *(u32*)(op + 32 + d0) = wB;
      }
  }
}

// ---------------- output projection (128x128 tile) ----------------
// grid 1028 = 257 x 4
__global__ __launch_bounds__(256)
void k_oproj(const u16* __restrict__ ab, const u16* __restrict__ wT, const float* __restrict__ bo,
             float* __restrict__ out){
  __shared__ u16 sh[16384];
  const int tid = threadIdx.x;
  const int lane = tid & 63, wid = tid >> 6;
  const int lg = lane >> 4, lr = lane & 15;
  const int wm = wid >> 1, wn = wid & 1;

  // bijective XCD swizzle (nwg=1028, q=128, r=4)
  int orig = blockIdx.x;
  int xcd = orig & 7, idx = orig >> 3;
  int wgid = (xcd < 4 ? xcd*129 : 516 + (xcd-4)*128) + idx;
  int mt = wgid >> 2, nt = wgid & 3;
  const int m0 = mt*128, n0 = nt*128;

  const int srow = tid >> 2;
  const int schunk = (tid & 3) ^ ((tid >> 3) & 3);
  const u16* asrc = ab + (size_t)(m0 + srow)*DIM_ + schunk*8;
  const u16* bsrc = wT + (size_t)(n0 + srow)*DIM_ + schunk*8;
  const int rsw = (lg ^ ((lr>>1)&3)) << 3;

  u16* As = sh;
  u16* Bs = sh + 8192;

  f32x4 acc[4][4];
#pragma unroll
  for (int m=0;m<4;++m)
#pragma unroll
    for (int n=0;n<4;++n) acc[m][n] = {0.f,0.f,0.f,0.f};

  gll16(asrc,            As + wid*512);
  gll16(asrc + 64*DIM_,  As + 2048 + wid*512);
  gll16(bsrc,            Bs + wid*512);
  gll16(bsrc + 64*DIM_,  Bs + 2048 + wid*512);

  for (int s=0; s<16; ++s){
    const int cur = s & 1;
    __syncthreads();
    if (s < 15){
      const int ko = (s+1)*32;
      gll16(asrc + ko,           As + (cur^1)*4096 + wid*512);
      gll16(asrc + ko + 64*DIM_, As + (cur^1)*4096 + 2048 + wid*512);
      gll16(bsrc + ko,           Bs + (cur^1)*4096 + wid*512);
      gll16(bsrc + ko + 64*DIM_, Bs + (cur^1)*4096 + 2048 + wid*512);
    }
    bf16x8 af[4], bf[4];
#pragma unroll
    for (int m=0;m<4;++m) af[m] = *(const bf16x8*)(As + cur*4096 + (64*wm+16*m+lr)*32 + rsw);
#pragma unroll
    for (int n=0;n<4;++n) bf[n] = *(const bf16x8*)(Bs + cur*4096 + (64*wn+16*n+lr)*32 + rsw);
    __builtin_amdgcn_s_setprio(1);
#pragma unroll
    for (int m=0;m<4;++m)
#pragma unroll
      for (int n=0;n<4;++n)
        acc[m][n] = __builtin_amdgcn_mfma_f32_16x16x32_bf16(af[m], bf[n], acc[m][n], 0, 0, 0);
    __builtin_amdgcn_s_setprio(0);
  }

  float bb[4];
#pragma unroll
  for (int n=0;n<4;++n) bb[n] = bo[n0 + 64*wn + 16*n + lr];
#pragma unroll
  for (int m=0;m<4;++m)
#pragma unroll
    for (int r=0;r<4;++r){
      int mg = m0 + 64*wm + 16*m + 4*lg + r;
      if (mg < M_){
#pragma unroll
        for (int n=0;n<4;++n)
          out[(size_t)mg*DIM_ + n0 + 64*wn + 16*n + lr] = acc[m][n][r] + bb[n];
      }
    }
}

// ---------------- launch ----------------
extern "C" void kernel_launch(void* const* d_in, const int* in_sizes, int n_in,
                              void* d_out, int out_size, void* d_ws, size_t ws_size,
                              hipStream_t stream) {
  const float* x     = (const float*)d_in[0];
  const float* w_qkv = (const float*)d_in[1];
  const float* g     = (const float*)d_in[2];
  const float* pe    = (const float*)d_in[3];
  const float* w_out = (const float*)d_in[4];
  const float* b_out = (const float*)d_in[5];
  const int*   bidx  = (const int*)d_in[6];
  float* out = (float*)d_out;

  char* ws = (char*)d_ws;
  u16*   xb    = (u16*)(ws);                    // 33,587,200  (aliased: aob reuses after k_qkv)
  u16*   wT    = (u16*)(ws + 33587200);         //  1,572,864
  u16*   woT   = (u16*)(ws + 35160064);         //    524,288
  u16*   qnb   = (u16*)(ws + 35684352);         // 37,748,736
  u16*   kn2   = (u16*)(ws + 73433088);         // 35,651,584
  u16*   v2    = (u16*)(ws + 109084672);        // 35,651,584
  float* biasf = (float*)(ws + 144736256);      // 40,108,032  (end 184,844,288)
  u16*   aob   = xb;                            // alias: xb dead after k_qkv

  int n4 = (B_*N_*DIM_)/4;
  k_conv_x<<<(n4+255)/256, 256, 0, stream>>>(x, xb, n4);
  k_transpose<<<(1536*512+255)/256, 256, 0, stream>>>(w_qkv, wT, 512, 1536);
  k_transpose<<<(512*512+255)/256, 256, 0, stream>>>(w_out, woT, 512, 512);
  k_biasr<<<39168, 256, 0, stream>>>(bidx, pe, biasf);
  k_ztail<<<12096, 256, 0, stream>>>(qnb, kn2, v2);

  k_qkv<<<3084, 256, 0, stream>>>(xb, wT, g, qnb, kn2, v2);
  k_attn2<<<2304, 256, 0, stream>>>(qnb, kn2, v2, biasf, aob);
  k_oproj<<<1028, 256, 0, stream>>>(aob, woT, b_out, out);
}

// Round 8
// 311.682 us; speedup vs baseline: 1.1724x; 1.1724x over previous
//
#include <hip/hip_runtime.h>

typedef short bf16x8 __attribute__((ext_vector_type(8)));
typedef float f32x4 __attribute__((ext_vector_type(4)));
typedef float f32x16 __attribute__((ext_vector_type(16)));
typedef unsigned int u32;
typedef u32 u32x4 __attribute__((ext_vector_type(4)));
typedef unsigned short u16;

#define B_    32
#define N_    1025
#define H_    8
#define DIM_  512
#define M_    (B_*N_)      // 32800
#define QP_   1152         // qn row pitch per bh
#define BIP_  1152         // bias_r i pitch
#define NT_   34           // KV/bias tiles incl. 1 pad tile (prefetch guard-free)
#define KVSZ_ (NT_*2048)   // per-bh u16 size of kn2/v2
#define BT_   (BIP_*32)    // bias tile stride (u16 elements)
#define SCALE_ 0.125f
#define LOG2E_ 1.4426950408889634f

__device__ __forceinline__ u16 f2bf(float f){
  unsigned u = __builtin_bit_cast(unsigned, f);
  u += 0x7FFFu + ((u >> 16) & 1u);
  return (u16)(u >> 16);
}
__device__ __forceinline__ u32 cvtpk(float a, float b){
  u32 r;
  asm("v_cvt_pk_bf16_f32 %0, %1, %2" : "=v"(r) : "v"(a), "v"(b));
  return r;
}
__device__ __forceinline__ void pswap(u32 &a, u32 &b){
  asm("v_permlane32_swap_b32 %0, %1" : "+v"(a), "+v"(b));
}
__device__ __forceinline__ void gll16(const u16* g, u16* l){
  __builtin_amdgcn_global_load_lds((const __attribute__((address_space(1))) u16*)(g),
                                   (__attribute__((address_space(3))) u16*)(l), 16, 0, 0);
}

// ---------------- prep kernels ----------------
__global__ __launch_bounds__(256)
void k_conv_x(const float* __restrict__ x, u16* __restrict__ o, int n4){
  int i = blockIdx.x*256 + threadIdx.x;
  if (i >= n4) return;
  float4 v = ((const float4*)x)[i];
  ushort4 r;
  r.x = f2bf(v.x); r.y = f2bf(v.y); r.z = f2bf(v.z); r.w = f2bf(v.w);
  ((ushort4*)o)[i] = r;
}

__global__ __launch_bounds__(256)
void k_transpose(const float* __restrict__ w, u16* __restrict__ wt, int R, int C){
  int i = blockIdx.x*256 + threadIdx.x;
  if (i >= R*C) return;
  int n = i / R, k = i - n*R;
  wt[i] = f2bf(w[k*C + n]);
}

// bias_r[h][tj(34)][i(1152)][hi(2)][16 regs] bf16; value = pe*log2e (masked; no offset)
__global__ __launch_bounds__(256)
void k_biasr(const int* __restrict__ idx, const float* __restrict__ pe, u16* __restrict__ br){
  int i_lin = blockIdx.x*256 + threadIdx.x;  // 8*34*1152*32 total
  int v = i_lin & 15, hi = (i_lin>>4)&1;
  int t1 = i_lin >> 5;
  int i = t1 % 1152;
  int t2 = t1 / 1152;
  int tj = t2 % NT_;
  int h = t2 / NT_;
  int j = tj*32 + (v&3) + 8*(v>>2) + 4*hi;
  float val;
  if (j >= 1 && j <= 1024 && i >= 1 && i <= 1024)
    val = pe[idx[(i-1)*1024 + (j-1)]*8 + h] * LOG2E_;
  else
    val = (j <= 1024) ? 0.f : -1e9f;
  br[i_lin] = f2bf(val);
}

// zero tails: qn rows [1025,1152); kn2 tile-32 j in [1025,1056); v2 same
__global__ __launch_bounds__(256)
void k_ztail(u16* __restrict__ qn, u16* __restrict__ kn2, u16* __restrict__ v2){
  int i = blockIdx.x*256 + threadIdx.x;
  if (i < 2080768){
    int bh = i / (127*64); int r = i - bh*(127*64);
    qn[((size_t)bh*QP_ + 1025 + (r>>6))*64 + (r&63)] = 0;
  } else if (i < 2588672){
    int k = i - 2080768; int bh = k/1984; int r = k - bh*1984;
    int n = 1025 + (r>>6), d = r & 63;
    kn2[(size_t)bh*KVSZ_ + 65536 + ((d>>3)<<8) + ((n&31)<<3) + (d&7)] = 0;
  } else if (i < 3096576){
    int k = i - 2588672; int bh = k/1984; int r = k - bh*1984;
    int n = 1025 + (r>>6), d = r & 63;
    v2[(size_t)bh*KVSZ_ + 65536 + (((n>>3)&3)<<9) + (d<<3) + (n&7)] = 0;
  }
}

// ---------------- QKV GEMM (128x128 tile) + fused RMSNorm / rearrange ----------------
// grid 3084 = 257 M-tiles x 12 N-tiles; 4 waves 2x2, each 64x64 quadrant
// q/k N-tiles use SWAPPED mfma operands so D rows = d (vectorized 8B stores);
// v N-tiles keep original order (j-runs match v2 layout).
__global__ __launch_bounds__(256)
void k_qkv(const u16* __restrict__ xb, const u16* __restrict__ wT, const float* __restrict__ g,
           u16* __restrict__ qn, u16* __restrict__ kn2, u16* __restrict__ v2){
  __shared__ u16 sh[16384];   // As[2][4096] | Bs[2][4096]
  const int tid = threadIdx.x;
  const int lane = tid & 63, wid = tid >> 6;
  const int lg = lane >> 4, lr = lane & 15;
  const int wm = wid >> 1, wn = wid & 1;

  // bijective XCD swizzle (nwg=3084, q=385, r=4); within XCD: nt fastest
  int orig = blockIdx.x;
  int xcd = orig & 7, idx = orig >> 3;
  int wgid = (xcd < 4 ? xcd*386 : 1544 + (xcd-4)*385) + idx;
  int mt = wgid / 12, nt = wgid - mt*12;
  const int m0 = mt*128, n0 = nt*128;
  const int qkv_t = nt >> 2;
  const int h = ((nt & 3) << 1) + wn;

  const int srow = tid >> 2;
  const int schunk = (tid & 3) ^ ((tid >> 3) & 3);
  const u16* asrc = xb + (size_t)(m0 + srow)*DIM_ + schunk*8;
  const u16* bsrc = wT + (size_t)(n0 + srow)*DIM_ + schunk*8;
  const int rsw = (lg ^ ((lr>>1)&3)) << 3;

  u16* As = sh;
  u16* Bs = sh + 8192;

  f32x4 acc[4][4];
#pragma unroll
  for (int m=0;m<4;++m)
#pragma unroll
    for (int n=0;n<4;++n) acc[m][n] = {0.f,0.f,0.f,0.f};

  gll16(asrc,            As + wid*512);
  gll16(asrc + 64*DIM_,  As + 2048 + wid*512);
  gll16(bsrc,            Bs + wid*512);
  gll16(bsrc + 64*DIM_,  Bs + 2048 + wid*512);

  for (int s=0; s<16; ++s){
    const int cur = s & 1;
    __syncthreads();
    if (s < 15){
      const int ko = (s+1)*32;
      gll16(asrc + ko,           As + (cur^1)*4096 + wid*512);
      gll16(asrc + ko + 64*DIM_, As + (cur^1)*4096 + 2048 + wid*512);
      gll16(bsrc + ko,           Bs + (cur^1)*4096 + wid*512);
      gll16(bsrc + ko + 64*DIM_, Bs + (cur^1)*4096 + 2048 + wid*512);
    }
    bf16x8 af[4], bf[4];
#pragma unroll
    for (int m=0;m<4;++m) af[m] = *(const bf16x8*)(As + cur*4096 + (64*wm+16*m+lr)*32 + rsw);
#pragma unroll
    for (int n=0;n<4;++n) bf[n] = *(const bf16x8*)(Bs + cur*4096 + (64*wn+16*n+lr)*32 + rsw);
    __builtin_amdgcn_s_setprio(1);
    if (qkv_t < 2){
#pragma unroll
      for (int m=0;m<4;++m)
#pragma unroll
        for (int n=0;n<4;++n)
          acc[m][n] = __builtin_amdgcn_mfma_f32_16x16x32_bf16(bf[n], af[m], acc[m][n], 0, 0, 0);
    } else {
#pragma unroll
      for (int m=0;m<4;++m)
#pragma unroll
        for (int n=0;n<4;++n)
          acc[m][n] = __builtin_amdgcn_mfma_f32_16x16x32_bf16(af[m], bf[n], acc[m][n], 0, 0, 0);
    }
    __builtin_amdgcn_s_setprio(0);
  }

  if (qkv_t < 2){
    // swapped layout: acc[m][n][r] at pos = 16m+lr (local), d = 16n+4lg+r
    const float extra = (qkv_t == 0) ? (SCALE_*LOG2E_) : 1.f;
    float4 gq[4];
#pragma unroll
    for (int n=0;n<4;++n) gq[n] = *(const float4*)&g[16*n + 4*lg];
#pragma unroll
    for (int m=0;m<4;++m){
      float s = 0.f;
#pragma unroll
      for (int n=0;n<4;++n)
#pragma unroll
        for (int r=0;r<4;++r) s += acc[m][n][r]*acc[m][n][r];
      s += __shfl_xor(s, 16); s += __shfl_xor(s, 32);
      float rstd = rsqrtf(s*(1.f/64.f) + 1e-6f) * extra;
      int mg = m0 + 64*wm + 16*m + lr;
      if (mg < M_){
        int b = mg / N_, pos = mg - b*N_;
        int bh = b*H_ + h;
#pragma unroll
        for (int n=0;n<4;++n){
          ushort4 pk;
          pk.x = f2bf(acc[m][n][0]*rstd*gq[n].x);
          pk.y = f2bf(acc[m][n][1]*rstd*gq[n].y);
          pk.z = f2bf(acc[m][n][2]*rstd*gq[n].z);
          pk.w = f2bf(acc[m][n][3]*rstd*gq[n].w);
          if (qkv_t == 0){
            *(ushort4*)(qn + ((size_t)bh*QP_ + pos)*64 + 16*n + 4*lg) = pk;
          } else {
            int dbase = 16*n + 4*lg;
            *(ushort4*)(kn2 + (size_t)bh*KVSZ_ + (pos>>5)*2048
                        + (dbase>>3)*256 + ((pos&31)<<3) + (dbase&7)) = pk;
          }
        }
      }
    }
  } else {
    // v: original layout, scalar stores (batch boundary breaks pos alignment)
#pragma unroll
    for (int m=0;m<4;++m)
#pragma unroll
      for (int r=0;r<4;++r){
        int mg = m0 + 64*wm + 16*m + 4*lg + r;
        if (mg < M_){
          int b = mg / N_, pos = mg - b*N_;
          int bh = b*H_ + h;
#pragma unroll
          for (int n=0;n<4;++n){
            int d = 16*n + lr;
            v2[(size_t)bh*KVSZ_ + (pos>>5)*2048 + (((pos>>3)&3)<<9) + (d<<3) + (pos&7)]
              = f2bf(acc[m][n][r]);
          }
        }
      }
  }
}

// ---------------- flash attention: fixed-max, bf16-bias-C-init, 2-tile pairs (round-5) ----
// grid 2304 = 8 XCD-chunks x (32 b x 9 qt); 4 waves x 32 q-rows = 128-row q-block
#define TILE(buf, off, B0, B1) do { \
  f32x16 s; \
  _Pragma("unroll") \
  for (int r=0;r<16;++r){ \
    u16 bv = (r < 8) ? ((u16)(B0)[r]) : ((u16)(B1)[r-8]); \
    s[r] = __builtin_bit_cast(float, ((u32)bv) << 16); \
  } \
  __builtin_amdgcn_s_setprio(1); \
  _Pragma("unroll") \
  for (int c=0;c<4;++c){ \
    bf16x8 kf = *(const bf16x8*)(&Ks[buf][0] + (off) + (2*c + hi)*256 + il*8); \
    s = __builtin_amdgcn_mfma_f32_32x32x16_bf16(kf, qf[c], s, 0, 0, 0); \
  } \
  __builtin_amdgcn_s_setprio(0); \
  _Pragma("unroll") \
  for (int r=0;r<16;++r) s[r] = __builtin_amdgcn_exp2f(s[r]); \
  u32 X0 = cvtpk(s[0],s[1]),   X1 = cvtpk(s[2],s[3]); \
  u32 Y0 = cvtpk(s[4],s[5]),   Y1 = cvtpk(s[6],s[7]); \
  u32 X2 = cvtpk(s[8],s[9]),   X3 = cvtpk(s[10],s[11]); \
  u32 Y2 = cvtpk(s[12],s[13]), Y3 = cvtpk(s[14],s[15]); \
  pswap(X0, Y0); pswap(X1, Y1); pswap(X2, Y2); pswap(X3, Y3); \
  u32x4 w0 = {X0, X1, Y0, Y1}; \
  u32x4 w1 = {X2, X3, Y2, Y3}; \
  bf16x8 pv0 = __builtin_bit_cast(bf16x8, w0); \
  bf16x8 pv1 = __builtin_bit_cast(bf16x8, w1); \
  __builtin_amdgcn_s_setprio(1); \
  _Pragma("unroll") \
  for (int c2=0;c2<2;++c2){ \
    bf16x8 pv = c2 ? pv1 : pv0; \
    const u16* vb = &Vs[buf][0] + (off) + (2*c2 + hi)*512; \
    bf16x8 vfA = *(const bf16x8*)(vb + il*8); \
    bf16x8 vfB = *(const bf16x8*)(vb + 256 + il*8); \
    oA = __builtin_amdgcn_mfma_f32_32x32x16_bf16(vfA, pv, oA, 0, 0, 0); \
    oB = __builtin_amdgcn_mfma_f32_32x32x16_bf16(vfB, pv, oB, 0, 0, 0); \
    oS = __builtin_amdgcn_mfma_f32_32x32x16_bf16(onesf, pv, oS, 0, 0, 0); \
  } \
  __builtin_amdgcn_s_setprio(0); \
} while(0)

__global__ __launch_bounds__(256, 3)
void k_attn2(const u16* __restrict__ qn, const u16* __restrict__ kn2, const u16* __restrict__ v2,
             const u16* __restrict__ br, u16* __restrict__ ao){
  __shared__ u16 Ks[2][4096];
  __shared__ u16 Vs[2][4096];
  const int tid = threadIdx.x;
  const int lane = tid & 63, wave = tid >> 6;
  const int il = lane & 31, hi = lane >> 5;
  int wg = ((blockIdx.x & 7) * 288) + (blockIdx.x >> 3);
  int h = wg / 288;
  int rem = wg - h*288;
  int b = rem / 9, qt = rem - (rem/9)*9;
  int bh = b*8 + h;
  int i0 = qt*128 + wave*32;

  // Q fragments (hoisted; q pre-scaled by SCALE*log2e in k_qkv)
  const u16* qp = qn + ((size_t)bh*QP_ + (i0 + il))*64 + hi*8;
  bf16x8 qf[4];
#pragma unroll
  for (int c=0;c<4;++c) qf[c] = *(const bf16x8*)(qp + 16*c);

  const u16* ksrc = kn2 + (size_t)bh*KVSZ_ + tid*8;
  const u16* vsrc = v2  + (size_t)bh*KVSZ_ + tid*8;

  // stage pair 0 (tiles 0,1) into buf 0
  gll16(ksrc,        &Ks[0][wave*512]);
  gll16(ksrc + 2048, &Ks[0][2048 + wave*512]);
  gll16(vsrc,        &Vs[0][wave*512]);
  gll16(vsrc + 2048, &Vs[0][2048 + wave*512]);

  f32x16 oA, oB, oS;
#pragma unroll
  for (int r=0;r<16;++r){ oA[r]=0.f; oB[r]=0.f; oS[r]=0.f; }

  const bf16x8 onesf = {0x3F80,0x3F80,0x3F80,0x3F80,0x3F80,0x3F80,0x3F80,0x3F80};

  const u16* bptr = br + ((size_t)(h*NT_)*BIP_ + (i0 + il))*32 + hi*16;
  bf16x8 cb0 = *(const bf16x8*)(bptr);
  bf16x8 cb1 = *(const bf16x8*)(bptr + 8);
  bf16x8 cb2 = *(const bf16x8*)(bptr + BT_);
  bf16x8 cb3 = *(const bf16x8*)(bptr + BT_ + 8);

  for (int t=0; t<16; ++t){
    const int cur = t & 1;
    __syncthreads();
    {
      const int base = (2*t+2)*2048;   // t=15 -> tiles 32,33 (pad tile valid)
      gll16(ksrc + base,        &Ks[cur^1][wave*512]);
      gll16(ksrc + base + 2048, &Ks[cur^1][2048 + wave*512]);
      gll16(vsrc + base,        &Vs[cur^1][wave*512]);
      gll16(vsrc + base + 2048, &Vs[cur^1][2048 + wave*512]);
    }
    TILE(cur, 0, cb0, cb1);
    cb0 = *(const bf16x8*)(bptr + 2*BT_);
    cb1 = *(const bf16x8*)(bptr + 2*BT_ + 8);
    TILE(cur, 2048, cb2, cb3);
    cb2 = *(const bf16x8*)(bptr + 3*BT_);
    cb3 = *(const bf16x8*)(bptr + 3*BT_ + 8);
    bptr += 2*BT_;
  }
  // tail: tile 32 in buf 0
  __syncthreads();
  TILE(0, 0, cb0, cb1);

  int i = i0 + il;
  if (i < N_){
    float inv = 1.f / oS[0];
    u16* op = ao + ((size_t)(b*N_ + i))*DIM_ + h*64;
#pragma unroll
    for (int q=0;q<4;++q)
#pragma unroll
      for (int pr=0;pr<2;++pr){
        int d0 = 8*q + 4*hi + 2*pr;
        u32 wA = cvtpk(oA[4*q+2*pr]*inv, oA[4*q+2*pr+1]*inv);
        u32 wB = cvtpk(oB[4*q+2*pr]*inv, oB[4*q+2*pr+1]*inv);
        *(u32*)(op + d0) = wA;
        *(u32*)(op + 32 + d0) = wB;
      }
  }
}

// ---------------- output projection (128x128 tile) ----------------
// grid 1028 = 257 x 4
__global__ __launch_bounds__(256)
void k_oproj(const u16* __restrict__ ab, const u16* __restrict__ wT, const float* __restrict__ bo,
             float* __restrict__ out){
  __shared__ u16 sh[16384];
  const int tid = threadIdx.x;
  const int lane = tid & 63, wid = tid >> 6;
  const int lg = lane >> 4, lr = lane & 15;
  const int wm = wid >> 1, wn = wid & 1;

  // bijective XCD swizzle (nwg=1028, q=128, r=4)
  int orig = blockIdx.x;
  int xcd = orig & 7, idx = orig >> 3;
  int wgid = (xcd < 4 ? xcd*129 : 516 + (xcd-4)*128) + idx;
  int mt = wgid >> 2, nt = wgid & 3;
  const int m0 = mt*128, n0 = nt*128;

  const int srow = tid >> 2;
  const int schunk = (tid & 3) ^ ((tid >> 3) & 3);
  const u16* asrc = ab + (size_t)(m0 + srow)*DIM_ + schunk*8;
  const u16* bsrc = wT + (size_t)(n0 + srow)*DIM_ + schunk*8;
  const int rsw = (lg ^ ((lr>>1)&3)) << 3;

  u16* As = sh;
  u16* Bs = sh + 8192;

  f32x4 acc[4][4];
#pragma unroll
  for (int m=0;m<4;++m)
#pragma unroll
    for (int n=0;n<4;++n) acc[m][n] = {0.f,0.f,0.f,0.f};

  gll16(asrc,            As + wid*512);
  gll16(asrc + 64*DIM_,  As + 2048 + wid*512);
  gll16(bsrc,            Bs + wid*512);
  gll16(bsrc + 64*DIM_,  Bs + 2048 + wid*512);

  for (int s=0; s<16; ++s){
    const int cur = s & 1;
    __syncthreads();
    if (s < 15){
      const int ko = (s+1)*32;
      gll16(asrc + ko,           As + (cur^1)*4096 + wid*512);
      gll16(asrc + ko + 64*DIM_, As + (cur^1)*4096 + 2048 + wid*512);
      gll16(bsrc + ko,           Bs + (cur^1)*4096 + wid*512);
      gll16(bsrc + ko + 64*DIM_, Bs + (cur^1)*4096 + 2048 + wid*512);
    }
    bf16x8 af[4], bf[4];
#pragma unroll
    for (int m=0;m<4;++m) af[m] = *(const bf16x8*)(As + cur*4096 + (64*wm+16*m+lr)*32 + rsw);
#pragma unroll
    for (int n=0;n<4;++n) bf[n] = *(const bf16x8*)(Bs + cur*4096 + (64*wn+16*n+lr)*32 + rsw);
    __builtin_amdgcn_s_setprio(1);
#pragma unroll
    for (int m=0;m<4;++m)
#pragma unroll
      for (int n=0;n<4;++n)
        acc[m][n] = __builtin_amdgcn_mfma_f32_16x16x32_bf16(af[m], bf[n], acc[m][n], 0, 0, 0);
    __builtin_amdgcn_s_setprio(0);
  }

  float bb[4];
#pragma unroll
  for (int n=0;n<4;++n) bb[n] = bo[n0 + 64*wn + 16*n + lr];
#pragma unroll
  for (int m=0;m<4;++m)
#pragma unroll
    for (int r=0;r<4;++r){
      int mg = m0 + 64*wm + 16*m + 4*lg + r;
      if (mg < M_){
#pragma unroll
        for (int n=0;n<4;++n)
          out[(size_t)mg*DIM_ + n0 + 64*wn + 16*n + lr] = acc[m][n][r] + bb[n];
      }
    }
}

// ---------------- launch ----------------
extern "C" void kernel_launch(void* const* d_in, const int* in_sizes, int n_in,
                              void* d_out, int out_size, void* d_ws, size_t ws_size,
                              hipStream_t stream) {
  const float* x     = (const float*)d_in[0];
  const float* w_qkv = (const float*)d_in[1];
  const float* g     = (const float*)d_in[2];
  const float* pe    = (const float*)d_in[3];
  const float* w_out = (const float*)d_in[4];
  const float* b_out = (const float*)d_in[5];
  const int*   bidx  = (const int*)d_in[6];
  float* out = (float*)d_out;

  char* ws = (char*)d_ws;
  u16*   xb    = (u16*)(ws);                    // 33,587,200  (aliased: aob reuses after k_qkv)
  u16*   wT    = (u16*)(ws + 33587200);         //  1,572,864
  u16*   woT   = (u16*)(ws + 35160064);         //    524,288
  u16*   qnb   = (u16*)(ws + 35684352);         // 37,748,736
  u16*   kn2   = (u16*)(ws + 73433088);         // 35,651,584
  u16*   v2    = (u16*)(ws + 109084672);        // 35,651,584
  u16*   biasr = (u16*)(ws + 144736256);        // 20,054,016  (end 164,790,272)
  u16*   aob   = xb;                            // alias: xb dead after k_qkv

  int n4 = (B_*N_*DIM_)/4;
  k_conv_x<<<(n4+255)/256, 256, 0, stream>>>(x, xb, n4);
  k_transpose<<<(1536*512+255)/256, 256, 0, stream>>>(w_qkv, wT, 512, 1536);
  k_transpose<<<(512*512+255)/256, 256, 0, stream>>>(w_out, woT, 512, 512);
  k_biasr<<<39168, 256, 0, stream>>>(bidx, pe, biasr);
  k_ztail<<<12096, 256, 0, stream>>>(qnb, kn2, v2);

  k_qkv<<<3084, 256, 0, stream>>>(xb, wT, g, qnb, kn2, v2);
  k_attn2<<<2304, 256, 0, stream>>>(qnb, kn2, v2, biasr, aob);
  k_oproj<<<1028, 256, 0, stream>>>(aob, woT, b_out, out);
}

// Round 9
// 275.630 us; speedup vs baseline: 1.3258x; 1.1308x over previous
//
#include <hip/hip_runtime.h>

typedef short bf16x8 __attribute__((ext_vector_type(8)));
typedef float f32x4 __attribute__((ext_vector_type(4)));
typedef float f32x16 __attribute__((ext_vector_type(16)));
typedef unsigned int u32;
typedef u32 u32x4 __attribute__((ext_vector_type(4)));
typedef unsigned short u16;

#define B_    32
#define N_    1025
#define H_    8
#define DIM_  512
#define M_    (B_*N_)      // 32800
#define QP_   1152         // qn row pitch per bh
#define BIP_  1152         // bias_r i pitch
#define NT_   34           // KV/bias tiles incl. 1 pad tile (prefetch guard-free)
#define KVSZ_ (NT_*2048)   // per-bh u16 size of kn2/v2
#define BT_   (BIP_*32)    // bias tile stride (u16 elements)
#define SCALE_ 0.125f
#define LOG2E_ 1.4426950408889634f

// fused-prep section sizes
#define CONVN_ (M_*DIM_/4)          // 4,198,400
#define TQKV_  (512*1536)           // 786,432
#define TOUT_  (512*512)            // 262,144
#define NBIAS_ (8*NT_*1152*32)      // 10,027,008
#define NZT_   3096576
#define PREP_TOTAL_ (CONVN_+TQKV_+TOUT_+NBIAS_+NZT_)   // 18,370,560 -> 71,760 blocks

__device__ __forceinline__ u16 f2bf(float f){
  unsigned u = __builtin_bit_cast(unsigned, f);
  u += 0x7FFFu + ((u >> 16) & 1u);
  return (u16)(u >> 16);
}
__device__ __forceinline__ u32 cvtpk(float a, float b){
  u32 r;
  asm("v_cvt_pk_bf16_f32 %0, %1, %2" : "=v"(r) : "v"(a), "v"(b));
  return r;
}
__device__ __forceinline__ void pswap(u32 &a, u32 &b){
  asm("v_permlane32_swap_b32 %0, %1" : "+v"(a), "+v"(b));
}
__device__ __forceinline__ void gll16(const u16* g, u16* l){
  __builtin_amdgcn_global_load_lds((const __attribute__((address_space(1))) u16*)(g),
                                   (__attribute__((address_space(3))) u16*)(l), 16, 0, 0);
}

// ---------------- fused prep kernel ----------------
__global__ __launch_bounds__(256)
void k_prep(const float* __restrict__ x, const float* __restrict__ wqkv,
            const float* __restrict__ wout, const int* __restrict__ idx,
            const float* __restrict__ pe,
            u16* __restrict__ xb, u16* __restrict__ wT, u16* __restrict__ woT,
            u16* __restrict__ br,
            u16* __restrict__ qn, u16* __restrict__ kn2, u16* __restrict__ v2){
  int i = blockIdx.x*256 + threadIdx.x;
  if (i < CONVN_){
    float4 v = ((const float4*)x)[i];
    ushort4 r;
    r.x = f2bf(v.x); r.y = f2bf(v.y); r.z = f2bf(v.z); r.w = f2bf(v.w);
    ((ushort4*)xb)[i] = r;
  } else if (i < CONVN_+TQKV_){
    int j = i - CONVN_;
    int n = j / 512, k = j - n*512;
    wT[j] = f2bf(wqkv[k*1536 + n]);
  } else if (i < CONVN_+TQKV_+TOUT_){
    int j = i - (CONVN_+TQKV_);
    int n = j / 512, k = j - n*512;
    woT[j] = f2bf(wout[k*512 + n]);
  } else if (i < CONVN_+TQKV_+TOUT_+NBIAS_){
    int j = i - (CONVN_+TQKV_+TOUT_);
    int v = j & 15, hi = (j>>4)&1;
    int t1 = j >> 5;
    int ii = t1 % 1152;
    int t2 = t1 / 1152;
    int tj = t2 % NT_;
    int h = t2 / NT_;
    int jj = tj*32 + (v&3) + 8*(v>>2) + 4*hi;
    float val;
    if (jj >= 1 && jj <= 1024 && ii >= 1 && ii <= 1024)
      val = pe[idx[(ii-1)*1024 + (jj-1)]*8 + h] * LOG2E_;
    else
      val = (jj <= 1024) ? 0.f : -1e9f;
    br[j] = f2bf(val);
  } else {
    int j = i - (CONVN_+TQKV_+TOUT_+NBIAS_);
    if (j < 2080768){
      int bh = j / (127*64); int r = j - bh*(127*64);
      qn[((size_t)bh*QP_ + 1025 + (r>>6))*64 + (r&63)] = 0;
    } else if (j < 2588672){
      int k = j - 2080768; int bh = k/1984; int r = k - bh*1984;
      int n = 1025 + (r>>6), d = r & 63;
      kn2[(size_t)bh*KVSZ_ + 65536 + ((d>>3)<<8) + ((n&31)<<3) + (d&7)] = 0;
    } else if (j < 3096576){
      int k = j - 2588672; int bh = k/1984; int r = k - bh*1984;
      int n = 1025 + (r>>6), d = r & 63;
      v2[(size_t)bh*KVSZ_ + 65536 + (((n>>3)&3)<<9) + (d<<3) + (n&7)] = 0;
    }
  }
}

// ---------------- QKV GEMM (128x128 tile) + fused RMSNorm / rearrange ----------------
// grid 3084 = 257 M-tiles x 12 N-tiles; 4 waves 2x2, each 64x64 quadrant
__global__ __launch_bounds__(256, 4)
void k_qkv(const u16* __restrict__ xb, const u16* __restrict__ wT, const float* __restrict__ g,
           u16* __restrict__ qn, u16* __restrict__ kn2, u16* __restrict__ v2){
  __shared__ u16 sh[16384];   // As[2][4096] | Bs[2][4096]
  const int tid = threadIdx.x;
  const int lane = tid & 63, wid = tid >> 6;
  const int lg = lane >> 4, lr = lane & 15;
  const int wm = wid >> 1, wn = wid & 1;

  // bijective XCD swizzle (nwg=3084, q=385, r=4); within XCD: nt fastest
  int orig = blockIdx.x;
  int xcd = orig & 7, idx = orig >> 3;
  int wgid = (xcd < 4 ? xcd*386 : 1544 + (xcd-4)*385) + idx;
  int mt = wgid / 12, nt = wgid - mt*12;
  const int m0 = mt*128, n0 = nt*128;
  const int qkv_t = nt >> 2;
  const int h = ((nt & 3) << 1) + wn;

  const int srow = tid >> 2;
  const int schunk = (tid & 3) ^ ((tid >> 3) & 3);
  const u16* asrc = xb + (size_t)(m0 + srow)*DIM_ + schunk*8;
  const u16* bsrc = wT + (size_t)(n0 + srow)*DIM_ + schunk*8;
  const int rsw = (lg ^ ((lr>>1)&3)) << 3;

  u16* As = sh;
  u16* Bs = sh + 8192;

  f32x4 acc[4][4];
#pragma unroll
  for (int m=0;m<4;++m)
#pragma unroll
    for (int n=0;n<4;++n) acc[m][n] = {0.f,0.f,0.f,0.f};

  gll16(asrc,            As + wid*512);
  gll16(asrc + 64*DIM_,  As + 2048 + wid*512);
  gll16(bsrc,            Bs + wid*512);
  gll16(bsrc + 64*DIM_,  Bs + 2048 + wid*512);

  for (int s=0; s<16; ++s){
    const int cur = s & 1;
    __syncthreads();
    if (s < 15){
      const int ko = (s+1)*32;
      gll16(asrc + ko,           As + (cur^1)*4096 + wid*512);
      gll16(asrc + ko + 64*DIM_, As + (cur^1)*4096 + 2048 + wid*512);
      gll16(bsrc + ko,           Bs + (cur^1)*4096 + wid*512);
      gll16(bsrc + ko + 64*DIM_, Bs + (cur^1)*4096 + 2048 + wid*512);
    }
    bf16x8 af[4], bf[4];
#pragma unroll
    for (int m=0;m<4;++m) af[m] = *(const bf16x8*)(As + cur*4096 + (64*wm+16*m+lr)*32 + rsw);
#pragma unroll
    for (int n=0;n<4;++n) bf[n] = *(const bf16x8*)(Bs + cur*4096 + (64*wn+16*n+lr)*32 + rsw);
    __builtin_amdgcn_s_setprio(1);
#pragma unroll
    for (int m=0;m<4;++m)
#pragma unroll
      for (int n=0;n<4;++n)
        acc[m][n] = __builtin_amdgcn_mfma_f32_16x16x32_bf16(af[m], bf[n], acc[m][n], 0, 0, 0);
    __builtin_amdgcn_s_setprio(0);
  }

  // unified epilogue: rows 64*wm+16m+4lg+r, head h, d = 16n+lr
  float gv[4];
#pragma unroll
  for (int n=0;n<4;++n)
    gv[n] = (qkv_t==0) ? g[16*n+lr]*(SCALE_*LOG2E_) : (qkv_t==1 ? g[16*n+lr] : 1.f);

#pragma unroll
  for (int m=0;m<4;++m){
    float rstd[4];
    if (qkv_t < 2){
#pragma unroll
      for (int r=0;r<4;++r){
        float s = 0.f;
#pragma unroll
        for (int n=0;n<4;++n) s += acc[m][n][r]*acc[m][n][r];
        s += __shfl_xor(s, 1); s += __shfl_xor(s, 2);
        s += __shfl_xor(s, 4); s += __shfl_xor(s, 8);
        rstd[r] = rsqrtf(s*(1.f/64.f) + 1e-6f);
      }
    } else {
#pragma unroll
      for (int r=0;r<4;++r) rstd[r] = 1.f;
    }
#pragma unroll
    for (int r=0;r<4;++r){
      int mg = m0 + 64*wm + 16*m + 4*lg + r;
      if (mg < M_){
        int b = mg / N_, pos = mg - b*N_;
        int bh = b*H_ + h;
#pragma unroll
        for (int n=0;n<4;++n){
          int d = 16*n + lr;
          u16 val = f2bf(acc[m][n][r]*rstd[r]*gv[n]);
          if (qkv_t == 0)
            qn[((size_t)bh*QP_ + pos)*64 + d] = val;
          else if (qkv_t == 1)
            kn2[(size_t)bh*KVSZ_ + (pos>>5)*2048 + ((d>>3)<<8) + ((pos&31)<<3) + (d&7)] = val;
          else
            v2[(size_t)bh*KVSZ_ + (pos>>5)*2048 + (((pos>>3)&3)<<9) + (d<<3) + (pos&7)] = val;
        }
      }
    }
  }
}

// ---------------- flash attention: fixed-max, bf16-bias-C-init, 2-tile pairs ----
// grid 2304 = 8 XCD-chunks x (32 b x 9 qt); 4 waves x 32 q-rows = 128-row q-block
// waves whose 32 rows are all padding skip compute (staging+barriers only)
#define TILE(buf, off, B0, B1) do { \
  f32x16 s; \
  _Pragma("unroll") \
  for (int r=0;r<16;++r){ \
    u16 bv = (r < 8) ? ((u16)(B0)[r]) : ((u16)(B1)[r-8]); \
    s[r] = __builtin_bit_cast(float, ((u32)bv) << 16); \
  } \
  __builtin_amdgcn_s_setprio(1); \
  _Pragma("unroll") \
  for (int c=0;c<4;++c){ \
    bf16x8 kf = *(const bf16x8*)(&Ks[buf][0] + (off) + (2*c + hi)*256 + il*8); \
    s = __builtin_amdgcn_mfma_f32_32x32x16_bf16(kf, qf[c], s, 0, 0, 0); \
  } \
  __builtin_amdgcn_s_setprio(0); \
  _Pragma("unroll") \
  for (int r=0;r<16;++r) s[r] = __builtin_amdgcn_exp2f(s[r]); \
  u32 X0 = cvtpk(s[0],s[1]),   X1 = cvtpk(s[2],s[3]); \
  u32 Y0 = cvtpk(s[4],s[5]),   Y1 = cvtpk(s[6],s[7]); \
  u32 X2 = cvtpk(s[8],s[9]),   X3 = cvtpk(s[10],s[11]); \
  u32 Y2 = cvtpk(s[12],s[13]), Y3 = cvtpk(s[14],s[15]); \
  pswap(X0, Y0); pswap(X1, Y1); pswap(X2, Y2); pswap(X3, Y3); \
  u32x4 w0 = {X0, X1, Y0, Y1}; \
  u32x4 w1 = {X2, X3, Y2, Y3}; \
  bf16x8 pv0 = __builtin_bit_cast(bf16x8, w0); \
  bf16x8 pv1 = __builtin_bit_cast(bf16x8, w1); \
  __builtin_amdgcn_s_setprio(1); \
  _Pragma("unroll") \
  for (int c2=0;c2<2;++c2){ \
    bf16x8 pv = c2 ? pv1 : pv0; \
    const u16* vb = &Vs[buf][0] + (off) + (2*c2 + hi)*512; \
    bf16x8 vfA = *(const bf16x8*)(vb + il*8); \
    bf16x8 vfB = *(const bf16x8*)(vb + 256 + il*8); \
    oA = __builtin_amdgcn_mfma_f32_32x32x16_bf16(vfA, pv, oA, 0, 0, 0); \
    oB = __builtin_amdgcn_mfma_f32_32x32x16_bf16(vfB, pv, oB, 0, 0, 0); \
    oS = __builtin_amdgcn_mfma_f32_32x32x16_bf16(onesf, pv, oS, 0, 0, 0); \
  } \
  __builtin_amdgcn_s_setprio(0); \
} while(0)

__global__ __launch_bounds__(256, 3)
void k_attn2(const u16* __restrict__ qn, const u16* __restrict__ kn2, const u16* __restrict__ v2,
             const u16* __restrict__ br, u16* __restrict__ ao){
  __shared__ u16 Ks[2][4096];
  __shared__ u16 Vs[2][4096];
  const int tid = threadIdx.x;
  const int lane = tid & 63, wave = tid >> 6;
  const int il = lane & 31, hi = lane >> 5;
  int wg = ((blockIdx.x & 7) * 288) + (blockIdx.x >> 3);
  int h = wg / 288;
  int rem = wg - h*288;
  int b = rem / 9, qt = rem - (rem/9)*9;
  int bh = b*8 + h;
  int i0 = qt*128 + wave*32;
  const bool active = (i0 <= 1024);

  // Q fragments (hoisted; q pre-scaled by SCALE*log2e in k_qkv)
  const u16* qp = qn + ((size_t)bh*QP_ + (i0 + il))*64 + hi*8;
  bf16x8 qf[4];
#pragma unroll
  for (int c=0;c<4;++c) qf[c] = *(const bf16x8*)(qp + 16*c);

  const u16* ksrc = kn2 + (size_t)bh*KVSZ_ + tid*8;
  const u16* vsrc = v2  + (size_t)bh*KVSZ_ + tid*8;

  // stage pair 0 (tiles 0,1) into buf 0
  gll16(ksrc,        &Ks[0][wave*512]);
  gll16(ksrc + 2048, &Ks[0][2048 + wave*512]);
  gll16(vsrc,        &Vs[0][wave*512]);
  gll16(vsrc + 2048, &Vs[0][2048 + wave*512]);

  f32x16 oA, oB, oS;
#pragma unroll
  for (int r=0;r<16;++r){ oA[r]=0.f; oB[r]=0.f; oS[r]=0.f; }

  const bf16x8 onesf = {0x3F80,0x3F80,0x3F80,0x3F80,0x3F80,0x3F80,0x3F80,0x3F80};

  const u16* bptr = br + ((size_t)(h*NT_)*BIP_ + (i0 + il))*32 + hi*16;
  bf16x8 cb0 = *(const bf16x8*)(bptr);
  bf16x8 cb1 = *(const bf16x8*)(bptr + 8);
  bf16x8 cb2 = *(const bf16x8*)(bptr + BT_);
  bf16x8 cb3 = *(const bf16x8*)(bptr + BT_ + 8);

  for (int t=0; t<16; ++t){
    const int cur = t & 1;
    __syncthreads();
    {
      const int base = (2*t+2)*2048;   // t=15 -> tiles 32,33 (pad tile valid)
      gll16(ksrc + base,        &Ks[cur^1][wave*512]);
      gll16(ksrc + base + 2048, &Ks[cur^1][2048 + wave*512]);
      gll16(vsrc + base,        &Vs[cur^1][wave*512]);
      gll16(vsrc + base + 2048, &Vs[cur^1][2048 + wave*512]);
    }
    if (active){
      TILE(cur, 0, cb0, cb1);
      cb0 = *(const bf16x8*)(bptr + 2*BT_);
      cb1 = *(const bf16x8*)(bptr + 2*BT_ + 8);
      TILE(cur, 2048, cb2, cb3);
      cb2 = *(const bf16x8*)(bptr + 3*BT_);
      cb3 = *(const bf16x8*)(bptr + 3*BT_ + 8);
      bptr += 2*BT_;
    }
  }
  // tail: tile 32 in buf 0
  __syncthreads();
  if (active){
    TILE(0, 0, cb0, cb1);
  }

  int i = i0 + il;
  if (i < N_){
    float inv = 1.f / oS[0];
    u16* op = ao + ((size_t)(b*N_ + i))*DIM_ + h*64;
#pragma unroll
    for (int q=0;q<4;++q)
#pragma unroll
      for (int pr=0;pr<2;++pr){
        int d0 = 8*q + 4*hi + 2*pr;
        u32 wA = cvtpk(oA[4*q+2*pr]*inv, oA[4*q+2*pr+1]*inv);
        u32 wB = cvtpk(oB[4*q+2*pr]*inv, oB[4*q+2*pr+1]*inv);
        *(u32*)(op + d0) = wA;
        *(u32*)(op + 32 + d0) = wB;
      }
  }
}

// ---------------- output projection (128x128 tile) ----------------
// grid 1028 = 257 x 4
__global__ __launch_bounds__(256)
void k_oproj(const u16* __restrict__ ab, const u16* __restrict__ wT, const float* __restrict__ bo,
             float* __restrict__ out){
  __shared__ u16 sh[16384];
  const int tid = threadIdx.x;
  const int lane = tid & 63, wid = tid >> 6;
  const int lg = lane >> 4, lr = lane & 15;
  const int wm = wid >> 1, wn = wid & 1;

  // bijective XCD swizzle (nwg=1028, q=128, r=4)
  int orig = blockIdx.x;
  int xcd = orig & 7, idx = orig >> 3;
  int wgid = (xcd < 4 ? xcd*129 : 516 + (xcd-4)*128) + idx;
  int mt = wgid >> 2, nt = wgid & 3;
  const int m0 = mt*128, n0 = nt*128;

  const int srow = tid >> 2;
  const int schunk = (tid & 3) ^ ((tid >> 3) & 3);
  const u16* asrc = ab + (size_t)(m0 + srow)*DIM_ + schunk*8;
  const u16* bsrc = wT + (size_t)(n0 + srow)*DIM_ + schunk*8;
  const int rsw = (lg ^ ((lr>>1)&3)) << 3;

  u16* As = sh;
  u16* Bs = sh + 8192;

  f32x4 acc[4][4];
#pragma unroll
  for (int m=0;m<4;++m)
#pragma unroll
    for (int n=0;n<4;++n) acc[m][n] = {0.f,0.f,0.f,0.f};

  gll16(asrc,            As + wid*512);
  gll16(asrc + 64*DIM_,  As + 2048 + wid*512);
  gll16(bsrc,            Bs + wid*512);
  gll16(bsrc + 64*DIM_,  Bs + 2048 + wid*512);

  for (int s=0; s<16; ++s){
    const int cur = s & 1;
    __syncthreads();
    if (s < 15){
      const int ko = (s+1)*32;
      gll16(asrc + ko,           As + (cur^1)*4096 + wid*512);
      gll16(asrc + ko + 64*DIM_, As + (cur^1)*4096 + 2048 + wid*512);
      gll16(bsrc + ko,           Bs + (cur^1)*4096 + wid*512);
      gll16(bsrc + ko + 64*DIM_, Bs + (cur^1)*4096 + 2048 + wid*512);
    }
    bf16x8 af[4], bf[4];
#pragma unroll
    for (int m=0;m<4;++m) af[m] = *(const bf16x8*)(As + cur*4096 + (64*wm+16*m+lr)*32 + rsw);
#pragma unroll
    for (int n=0;n<4;++n) bf[n] = *(const bf16x8*)(Bs + cur*4096 + (64*wn+16*n+lr)*32 + rsw);
    __builtin_amdgcn_s_setprio(1);
#pragma unroll
    for (int m=0;m<4;++m)
#pragma unroll
      for (int n=0;n<4;++n)
        acc[m][n] = __builtin_amdgcn_mfma_f32_16x16x32_bf16(af[m], bf[n], acc[m][n], 0, 0, 0);
    __builtin_amdgcn_s_setprio(0);
  }

  float bb[4];
#pragma unroll
  for (int n=0;n<4;++n) bb[n] = bo[n0 + 64*wn + 16*n + lr];
#pragma unroll
  for (int m=0;m<4;++m)
#pragma unroll
    for (int r=0;r<4;++r){
      int mg = m0 + 64*wm + 16*m + 4*lg + r;
      if (mg < M_){
#pragma unroll
        for (int n=0;n<4;++n)
          out[(size_t)mg*DIM_ + n0 + 64*wn + 16*n + lr] = acc[m][n][r] + bb[n];
      }
    }
}

// ---------------- launch ----------------
extern "C" void kernel_launch(void* const* d_in, const int* in_sizes, int n_in,
                              void* d_out, int out_size, void* d_ws, size_t ws_size,
                              hipStream_t stream) {
  const float* x     = (const float*)d_in[0];
  const float* w_qkv = (const float*)d_in[1];
  const float* g     = (const float*)d_in[2];
  const float* pe    = (const float*)d_in[3];
  const float* w_out = (const float*)d_in[4];
  const float* b_out = (const float*)d_in[5];
  const int*   bidx  = (const int*)d_in[6];
  float* out = (float*)d_out;

  char* ws = (char*)d_ws;
  u16*   xb    = (u16*)(ws);                    // 33,587,200  (aliased: aob reuses after k_qkv)
  u16*   wT    = (u16*)(ws + 33587200);         //  1,572,864
  u16*   woT   = (u16*)(ws + 35160064);         //    524,288
  u16*   qnb   = (u16*)(ws + 35684352);         // 37,748,736
  u16*   kn2   = (u16*)(ws + 73433088);         // 35,651,584
  u16*   v2    = (u16*)(ws + 109084672);        // 35,651,584
  u16*   biasr = (u16*)(ws + 144736256);        // 20,054,016  (end 164,790,272)
  u16*   aob   = xb;                            // alias: xb dead after k_qkv

  k_prep<<<PREP_TOTAL_/256, 256, 0, stream>>>(x, w_qkv, w_out, bidx, pe,
                                              xb, wT, woT, biasr, qnb, kn2, v2);
  k_qkv<<<3084, 256, 0, stream>>>(xb, wT, g, qnb, kn2, v2);
  k_attn2<<<2304, 256, 0, stream>>>(qnb, kn2, v2, biasr, aob);
  k_oproj<<<1028, 256, 0, stream>>>(aob, woT, b_out, out);
}